// Round 7
// baseline (179.635 us; speedup 1.0000x reference)
//
#include <hip/hip_runtime.h>
#include <hip/hip_fp16.h>

// Fused 3D local-NCC loss. Shapes (2,1,160,192,160) fp32,
// flat = ((n*D + d)*H + h)*W + w. 9x9x9 box window, zero-padded.
//
// v7: same skewed 3-stage pipeline as v6 (one lgkm-only barrier per plane),
// but all LDS intermediates are PACKED fp16 (h2 = 2 x _Float16):
//   A  (192 thr): prefetched I/J rows (float4 scalars) -> fp32 register
//      9-tap W-slide -> v_cvt_pkrtz pack -> ws[par] (h2, row stride 18).
//   A2 (160 thr): 2-wide sliding 9-tap H-sum entirely in v_pk_add_f16
//      (16 b32 reads + 8 b32 writes per thread) -> hw[par].
//   B  (512 thr): 5 u16 reads + cvt -> fp32 D sliding window -> cc.
// LDS bytes/plane: 65 KB -> 32.5 KB (the measured bottleneck).
// fp16 is safe: W-sums <= 9, H-sums <= 81; cc bias ~1e-5 << 5.8e-4 thr.

namespace {
constexpr int Wd = 160, Hd = 192, Dd = 160, NB = 2;
constexpr long DSTRIDE = (long)Hd * Wd;        // 30720
constexpr long VOLUME  = (long)Dd * DSTRIDE;   // 4,915,200
constexpr int BW = 32, BH = 16, BD = 28;
constexpr int EH = BH + 8;                     // 24 halo rows
constexpr int NWB = 5, NHB = 12, NDB = 6;      // 6*28=168 covers 160
constexpr int NBLK = NB * NDB * NHB * NWB;     // 720
constexpr int NT = 512;
constexpr int RS  = 18;                        // h2 row stride (16 + 2 pad)
constexpr int CHS = EH * RS;                   // 432 h2 per ws channel
constexpr int HWS = BH * RS;                   // 288 h2 per hw channel
constexpr float INV_WV = 1.0f / 729.0f;
constexpr float NEG_INV_TOTAL = -1.0f / 9830400.0f;
}

typedef _Float16 h2 __attribute__((ext_vector_type(2)));

__device__ __forceinline__ void bar_lds() {
    asm volatile("s_waitcnt lgkmcnt(0)\n\ts_barrier" ::: "memory");
}

__device__ __forceinline__ h2 pk(float lo, float hi) {
    return (h2)__builtin_amdgcn_cvt_pkrtz(lo, hi);   // v_cvt_pkrtz_f16_f32
}

__device__ __forceinline__ float4 slide9(float v0, float v1, float v2, float v3,
                                         float v4, float v5, float v6, float v7,
                                         float v8, float v9, float v10, float v11) {
    float s8 = ((v0 + v1) + (v2 + v3)) + ((v4 + v5) + (v6 + v7)) + v8;
    float4 o;
    o.x = s8;
    o.y = o.x + (v9 - v0);
    o.z = o.y + (v10 - v1);
    o.w = o.z + (v11 - v2);
    return o;
}

__global__ __launch_bounds__(NT) void k_ncc(const float* __restrict__ I,
                                            const float* __restrict__ J,
                                            float* __restrict__ out) {
    __shared__ h2 ws[2][5 * CHS];    // 17,280 B
    __shared__ h2 hw[2][5 * HWS];    // 11,520 B
    __shared__ float red[NT];        //  2,048 B

    const int tid = threadIdx.x;
    int bx = blockIdx.x;
    const int wb = bx % NWB; bx /= NWB;
    const int hb = bx % NHB; bx /= NHB;
    const int db = bx % NDB; bx /= NDB;
    const int n  = bx;
    const int w0 = wb * BW, h0 = hb * BH, d0 = db * BD;
    const long nvol = (long)n * VOLUME;

    // ---- Stage-A mapping (tid < 192): 24 rows x 8 four-wide segments ----
    const int seg = tid & 7;
    const int yy  = tid >> 3;
    const bool aJob = (tid < 192);
    const int ah    = h0 - 4 + yy;
    const int wbase = w0 - 4 + (seg << 2);
    const bool ahOk = aJob && ((unsigned)ah < (unsigned)Hd);
    const bool qok0 = ((unsigned)(wbase + 0) < (unsigned)Wd);
    const bool qok1 = ((unsigned)(wbase + 4) < (unsigned)Wd);
    const bool qok2 = ((unsigned)(wbase + 8) < (unsigned)Wd);
    const long roff = nvol + (long)ah * Wd + wbase + (long)(d0 - 4) * DSTRIDE;
    const float* aI = I + roff;
    const float* aJ = J + roff;
    const int aOff = yy * RS + (seg << 1);          // h2 index in ws channel

    // ---- Stage-A2 mapping (tid < 160): ch x 16 w-pairs x 2 h-halves ----
    const int c2  = tid >> 5;                       // 0..4
    const int wp  = tid & 15;                       // 0..15
    const int hq  = (tid >> 4) & 1;                 // 0..1
    const int a2src = c2 * CHS + (hq * 8) * RS + wp;
    const int a2dst = c2 * HWS + (hq * 8) * RS + wp;

    // ---- Stage-B mapping ----
    const int tx = tid & 31, ty = tid >> 5;
    const int bIdx16 = (ty * RS + (tx >> 1)) * 2 + (tx & 1);  // u16 idx in hw ch

    float4 pI0, pI1, pI2, pJ0, pJ1, pJ2;

#define ISSUE(PP)                                                            \
    do {                                                                     \
        const bool _pv = ahOk && ((unsigned)(PP) < (unsigned)Dd);            \
        pI0 = (_pv && qok0) ? *(const float4*)(aI + 0) : float4{0, 0, 0, 0}; \
        pI1 = (_pv && qok1) ? *(const float4*)(aI + 4) : float4{0, 0, 0, 0}; \
        pI2 = (_pv && qok2) ? *(const float4*)(aI + 8) : float4{0, 0, 0, 0}; \
        pJ0 = (_pv && qok0) ? *(const float4*)(aJ + 0) : float4{0, 0, 0, 0}; \
        pJ1 = (_pv && qok1) ? *(const float4*)(aJ + 4) : float4{0, 0, 0, 0}; \
        pJ2 = (_pv && qok2) ? *(const float4*)(aJ + 8) : float4{0, 0, 0, 0}; \
    } while (0)

#define STAGE_A(WSP, PV)                                                       \
    if ((PV) && aJob) {                                                        \
        const float a0 = pI0.x, a1 = pI0.y, a2 = pI0.z, a3 = pI0.w;            \
        const float a4 = pI1.x, a5 = pI1.y, a6 = pI1.z, a7 = pI1.w;            \
        const float a8 = pI2.x, a9 = pI2.y, a10 = pI2.z, a11 = pI2.w;          \
        const float b0 = pJ0.x, b1 = pJ0.y, b2 = pJ0.z, b3 = pJ0.w;            \
        const float b4 = pJ1.x, b5 = pJ1.y, b6 = pJ1.z, b7 = pJ1.w;            \
        const float b8 = pJ2.x, b9 = pJ2.y, b10 = pJ2.z, b11 = pJ2.w;          \
        h2* const wab = (WSP) + aOff;                                          \
        float4 o;                                                              \
        o = slide9(a0, a1, a2, a3, a4, a5, a6, a7, a8, a9, a10, a11);          \
        wab[0 * CHS + 0] = pk(o.x, o.y); wab[0 * CHS + 1] = pk(o.z, o.w);      \
        o = slide9(b0, b1, b2, b3, b4, b5, b6, b7, b8, b9, b10, b11);          \
        wab[1 * CHS + 0] = pk(o.x, o.y); wab[1 * CHS + 1] = pk(o.z, o.w);      \
        o = slide9(a0 * a0, a1 * a1, a2 * a2, a3 * a3, a4 * a4, a5 * a5,       \
                   a6 * a6, a7 * a7, a8 * a8, a9 * a9, a10 * a10, a11 * a11);  \
        wab[2 * CHS + 0] = pk(o.x, o.y); wab[2 * CHS + 1] = pk(o.z, o.w);      \
        o = slide9(b0 * b0, b1 * b1, b2 * b2, b3 * b3, b4 * b4, b5 * b5,       \
                   b6 * b6, b7 * b7, b8 * b8, b9 * b9, b10 * b10, b11 * b11);  \
        wab[3 * CHS + 0] = pk(o.x, o.y); wab[3 * CHS + 1] = pk(o.z, o.w);      \
        o = slide9(a0 * b0, a1 * b1, a2 * b2, a3 * b3, a4 * b4, a5 * b5,       \
                   a6 * b6, a7 * b7, a8 * b8, a9 * b9, a10 * b10, a11 * b11);  \
        wab[4 * CHS + 0] = pk(o.x, o.y); wab[4 * CHS + 1] = pk(o.z, o.w);      \
    }

#define STAGE_A2(WSR, HWW, PV)                                                 \
    if ((PV) && tid < 160) {                                                   \
        const h2* const src = (WSR) + a2src;                                   \
        h2* const dst = (HWW) + a2dst;                                         \
        const h2 g0 = src[0 * RS], g1 = src[1 * RS], g2 = src[2 * RS];         \
        const h2 g3 = src[3 * RS], g4 = src[4 * RS], g5 = src[5 * RS];         \
        const h2 g6 = src[6 * RS], g7 = src[7 * RS];                           \
        h2 s = ((g0 + g1) + (g2 + g3)) + ((g4 + g5) + (g6 + g7));              \
        s += src[ 8 * RS]; dst[0 * RS] = s; s -= g0;                           \
        s += src[ 9 * RS]; dst[1 * RS] = s; s -= g1;                           \
        s += src[10 * RS]; dst[2 * RS] = s; s -= g2;                           \
        s += src[11 * RS]; dst[3 * RS] = s; s -= g3;                           \
        s += src[12 * RS]; dst[4 * RS] = s; s -= g4;                           \
        s += src[13 * RS]; dst[5 * RS] = s; s -= g5;                           \
        s += src[14 * RS]; dst[6 * RS] = s; s -= g6;                           \
        s += src[15 * RS]; dst[7 * RS] = s;                                    \
    }

    float hist[9][5];
#pragma unroll
    for (int k = 0; k < 9; ++k)
#pragma unroll
        for (int c = 0; c < 5; ++c) hist[k][c] = 0.0f;
    float sa[5] = {0, 0, 0, 0, 0};
    float acc = 0.0f;

    ISSUE(d0 - 4);   // prime

    // ---- peel k=0: A only (plane d0-4 -> ws[0]) ----
    {
        const int pA = d0 - 4;
        STAGE_A(ws[0], (unsigned)pA < (unsigned)Dd);
        aI += DSTRIDE; aJ += DSTRIDE;
        ISSUE(pA + 1);
        bar_lds();
    }
    // ---- peel k=1: A (plane d0-3 -> ws[1]); A2 (plane d0-4: ws[0]->hw[0])
    {
        const int pA = d0 - 3;
        STAGE_A(ws[1], (unsigned)pA < (unsigned)Dd);
        aI += DSTRIDE; aJ += DSTRIDE;
        ISSUE(pA + 1);
        STAGE_A2(ws[0], hw[0], (unsigned)(d0 - 4) < (unsigned)Dd);
        bar_lds();
    }

#pragma unroll 1
    for (int M = 0; M < 4; ++M) {
        const int mpar = M & 1;
#pragma unroll
        for (int u = 0; u < 9; ++u) {
            const int t   = 9 * M + u;       // B's plane offset
            const int pB  = d0 - 4 + t;
            const int pA2 = pB + 1;
            const int pA  = pB + 2;
            const int parA  = (mpar + u) & 1;
            const int parA2 = (mpar + u + 1) & 1;

            // Stage A: plane pA -> ws[parA]
            STAGE_A(ws[parA], (t <= 33) && ((unsigned)pA < (unsigned)Dd));
            aI += DSTRIDE; aJ += DSTRIDE;
            if (M < 3 || u <= 5) { ISSUE(pA + 1); }

            // Stage A2: plane pA2: ws[parA2] -> hw[parA2]
            STAGE_A2(ws[parA2], hw[parA2],
                     (t <= 34) && ((unsigned)pA2 < (unsigned)Dd));

            // Stage B: plane pB from hw[parA] (written last iteration)
            float h5[5];
            if ((unsigned)pB < (unsigned)Dd) {
                const unsigned short* const hwu =
                    (const unsigned short*)hw[parA] + bIdx16;
#pragma unroll
                for (int c = 0; c < 5; ++c) {
                    const unsigned short v = hwu[c * (HWS * 2)];
                    h5[c] = (float)__builtin_bit_cast(_Float16, v);
                }
            } else {
#pragma unroll
                for (int c = 0; c < 5; ++c) h5[c] = 0.0f;
            }
#pragma unroll
            for (int c = 0; c < 5; ++c) sa[c] += h5[c];
            const int dout = d0 + t - 8;
            if (t >= 8 && dout < Dd) {
                const float cross = sa[4] - sa[0] * sa[1] * INV_WV;
                const float iv    = sa[2] - sa[0] * sa[0] * INV_WV;
                const float jv    = sa[3] - sa[1] * sa[1] * INV_WV;
                acc += (cross * cross) * __builtin_amdgcn_rcpf(iv * jv + 1e-5f);
            }
#pragma unroll
            for (int c = 0; c < 5; ++c) sa[c] -= hist[(u + 1) % 9][c];
#pragma unroll
            for (int c = 0; c < 5; ++c) hist[u][c] = h5[c];

            bar_lds();
        }
    }
#undef ISSUE
#undef STAGE_A
#undef STAGE_A2

    // ---- block reduction + global atomic (pre-scaled) ----
    red[tid] = acc;
    __syncthreads();
    for (int off = NT / 2; off > 0; off >>= 1) {
        if (tid < off) red[tid] += red[tid + off];
        __syncthreads();
    }
    if (tid == 0) atomicAdd(out, red[0] * NEG_INV_TOTAL);
}

extern "C" void kernel_launch(void* const* d_in, const int* in_sizes, int n_in,
                              void* d_out, int out_size, void* d_ws, size_t ws_size,
                              hipStream_t stream) {
    const float* I = (const float*)d_in[0];
    const float* J = (const float*)d_in[1];
    float* out = (float*)d_out;

    hipMemsetAsync(d_out, 0, sizeof(float), stream);   // stream-ordered, graph-safe
    k_ncc<<<NBLK, NT, 0, stream>>>(I, J, out);
}

// Round 8
// 160.030 us; speedup vs baseline: 1.1225x; 1.1225x over previous
//
#include <hip/hip_runtime.h>

// Fused 3D local-NCC loss. Shapes (2,1,160,192,160) fp32,
// flat = ((n*D + d)*H + h)*W + w. 9x9x9 box window, zero-padded.
//
// v8: v5 fp32 structure (fp16 LDS regressed: bank conflicts + VALU), with
// occupancy raised: 32(w) x 16(h) x 19(d) tile -> 1080 blocks (4.2/CU),
// 27 = 3x9 planes keeps the static 9-deep D-ring. A2 runs in float2
// (160 thr x 16 b64 reads + 8 b64 writes, half the wave-LDS instrs).
// LDS 27.6 KB + VGPR<=64 => 4 co-resident 512-thread blocks/CU.

namespace {
constexpr int Wd = 160, Hd = 192, Dd = 160, NB = 2;
constexpr long DSTRIDE = (long)Hd * Wd;        // 30720
constexpr long VOLUME  = (long)Dd * DSTRIDE;   // 4,915,200
constexpr int BW = 32, BH = 16, BD = 19;
constexpr int EH = BH + 8;                     // 24 halo rows
constexpr int NWB = 5, NHB = 12, NDB = 9;      // 9*19=171 covers 160
constexpr int NBLK = NB * NDB * NHB * NWB;     // 1080
constexpr int NT = 512;
constexpr int CH  = EH * BW;                   // 768 floats / channel (ws)
constexpr int HWC = BH * BW;                   // 512 floats / channel (hw)
constexpr int NPLANES = BD + 8;                // 27 = 3 * 9
constexpr float INV_WV = 1.0f / 729.0f;
constexpr float NEG_INV_TOTAL = -1.0f / 9830400.0f;
}

__device__ __forceinline__ void bar_lds() {
    asm volatile("s_waitcnt lgkmcnt(0)\n\ts_barrier" ::: "memory");
}

__device__ __forceinline__ float4 slide9(float v0, float v1, float v2, float v3,
                                         float v4, float v5, float v6, float v7,
                                         float v8, float v9, float v10, float v11) {
    float s8 = ((v0 + v1) + (v2 + v3)) + ((v4 + v5) + (v6 + v7)) + v8;
    float4 o;
    o.x = s8;
    o.y = o.x + (v9 - v0);
    o.z = o.y + (v10 - v1);
    o.w = o.z + (v11 - v2);
    return o;
}

__global__ __launch_bounds__(NT) void k_ncc(const float* __restrict__ I,
                                            const float* __restrict__ J,
                                            float* __restrict__ out) {
    __shared__ float ws[5 * CH];    // 15,360 B
    __shared__ float hw[5 * HWC];   // 10,240 B
    __shared__ float red[NT];       //  2,048 B

    const int tid = threadIdx.x;
    int bx = blockIdx.x;
    const int wb = bx % NWB; bx /= NWB;
    const int hb = bx % NHB; bx /= NHB;
    const int db = bx % NDB; bx /= NDB;
    const int n  = bx;
    const int w0 = wb * BW, h0 = hb * BH, d0 = db * BD;
    const long nvol = (long)n * VOLUME;

    // ---- Phase-A mapping (tid < 192): 24 rows x 8 four-wide segments ----
    const int seg = tid & 7;
    const int yy  = tid >> 3;
    const bool aJob = (tid < 192);
    const int ah    = h0 - 4 + yy;
    const int wbase = w0 - 4 + (seg << 2);
    const bool ahOk = aJob && ((unsigned)ah < (unsigned)Hd);
    const bool qok0 = ((unsigned)(wbase + 0) < (unsigned)Wd);
    const bool qok1 = ((unsigned)(wbase + 4) < (unsigned)Wd);
    const bool qok2 = ((unsigned)(wbase + 8) < (unsigned)Wd);
    const long roff = nvol + (long)ah * Wd + wbase + (long)(d0 - 4) * DSTRIDE;
    const float* aI = I + roff;
    const float* aJ = J + roff;

    // ---- Phase-A2 mapping (tid < 160), float2-wide ----
    const int c2 = tid >> 5;                 // channel 0..4
    const int wp = tid & 15;                 // float2 lane 0..15
    const int hq = (tid >> 4) & 1;           // h-half 0..1
    const float2* const a2srcB =
        (const float2*)(ws + c2 * CH) + (hq * 8) * 16 + wp;
    float2* const a2dstB = (float2*)(hw + c2 * HWC) + (hq * 8) * 16 + wp;

    // ---- Phase-B mapping ----
    const int tx = tid & 31, ty = tid >> 5;

    // Prefetch registers (explicit scalars -> never spilled).
    float4 pI0, pI1, pI2, pJ0, pJ1, pJ2;

#define ISSUE(PP)                                                            \
    do {                                                                     \
        const bool _pv = ahOk && ((unsigned)(PP) < (unsigned)Dd);            \
        pI0 = (_pv && qok0) ? *(const float4*)(aI + 0) : float4{0, 0, 0, 0}; \
        pI1 = (_pv && qok1) ? *(const float4*)(aI + 4) : float4{0, 0, 0, 0}; \
        pI2 = (_pv && qok2) ? *(const float4*)(aI + 8) : float4{0, 0, 0, 0}; \
        pJ0 = (_pv && qok0) ? *(const float4*)(aJ + 0) : float4{0, 0, 0, 0}; \
        pJ1 = (_pv && qok1) ? *(const float4*)(aJ + 4) : float4{0, 0, 0, 0}; \
        pJ2 = (_pv && qok2) ? *(const float4*)(aJ + 8) : float4{0, 0, 0, 0}; \
    } while (0)

    float hist[9][5];
#pragma unroll
    for (int k = 0; k < 9; ++k)
#pragma unroll
        for (int c = 0; c < 5; ++c) hist[k][c] = 0.0f;
    float sa[5] = {0, 0, 0, 0, 0};
    float acc = 0.0f;

    ISSUE(d0 - 4);   // prime

#pragma unroll 1
    for (int M = 0; M < 3; ++M) {
#pragma unroll
        for (int u = 0; u < 9; ++u) {
            const int t = 9 * M + u;
            const int p = d0 - 4 + t;
            const bool pvalid = ((unsigned)p < (unsigned)Dd);

            // ---------- Phase A: consume prefetch -> W-slide -> LDS ------
            if (pvalid && aJob) {
                const float a0 = pI0.x, a1 = pI0.y, a2 = pI0.z, a3 = pI0.w;
                const float a4 = pI1.x, a5 = pI1.y, a6 = pI1.z, a7 = pI1.w;
                const float a8 = pI2.x, a9 = pI2.y, a10 = pI2.z, a11 = pI2.w;
                const float b0 = pJ0.x, b1 = pJ0.y, b2 = pJ0.z, b3 = pJ0.w;
                const float b4 = pJ1.x, b5 = pJ1.y, b6 = pJ1.z, b7 = pJ1.w;
                const float b8 = pJ2.x, b9 = pJ2.y, b10 = pJ2.z, b11 = pJ2.w;
                float* const wab = ws + yy * BW + (seg << 2);
                *(float4*)(wab + 0 * CH) =
                    slide9(a0, a1, a2, a3, a4, a5, a6, a7, a8, a9, a10, a11);
                *(float4*)(wab + 1 * CH) =
                    slide9(b0, b1, b2, b3, b4, b5, b6, b7, b8, b9, b10, b11);
                *(float4*)(wab + 2 * CH) =
                    slide9(a0 * a0, a1 * a1, a2 * a2, a3 * a3, a4 * a4, a5 * a5,
                           a6 * a6, a7 * a7, a8 * a8, a9 * a9, a10 * a10, a11 * a11);
                *(float4*)(wab + 3 * CH) =
                    slide9(b0 * b0, b1 * b1, b2 * b2, b3 * b3, b4 * b4, b5 * b5,
                           b6 * b6, b7 * b7, b8 * b8, b9 * b9, b10 * b10, b11 * b11);
                *(float4*)(wab + 4 * CH) =
                    slide9(a0 * b0, a1 * b1, a2 * b2, a3 * b3, a4 * b4, a5 * b5,
                           a6 * b6, a7 * b7, a8 * b8, a9 * b9, a10 * b10, a11 * b11);
            }
            // Issue next plane's loads (in flight across both barriers).
            aI += DSTRIDE; aJ += DSTRIDE;
            if (t < NPLANES - 1) { ISSUE(p + 1); }

            bar_lds();

            // ---------- Phase A2: float2 sliding 9-tap H-sum -> hw -------
            if (pvalid && tid < 160) {
                const float2* const src = a2srcB;
                float2* const dst = a2dstB;
                const float2 g0 = src[0 * 16], g1 = src[1 * 16];
                const float2 g2 = src[2 * 16], g3 = src[3 * 16];
                const float2 g4 = src[4 * 16], g5 = src[5 * 16];
                const float2 g6 = src[6 * 16], g7 = src[7 * 16];
                float2 s;
                s.x = ((g0.x + g1.x) + (g2.x + g3.x)) + ((g4.x + g5.x) + (g6.x + g7.x));
                s.y = ((g0.y + g1.y) + (g2.y + g3.y)) + ((g4.y + g5.y) + (g6.y + g7.y));
                float2 r;
#define A2STEP(K, GK)                                                   \
                r = src[(K + 8) * 16];                                  \
                s.x += r.x; s.y += r.y;                                 \
                dst[K * 16] = s;                                        \
                s.x -= GK.x; s.y -= GK.y;
                A2STEP(0, g0) A2STEP(1, g1) A2STEP(2, g2) A2STEP(3, g3)
                A2STEP(4, g4) A2STEP(5, g5) A2STEP(6, g6)
#undef A2STEP
                r = src[15 * 16];
                s.x += r.x; s.y += r.y;
                dst[7 * 16] = s;
            }

            bar_lds();

            // ---------- Phase B: 5 reads + D-window + cc -----------------
            float h5[5];
            if (pvalid) {
#pragma unroll
                for (int c = 0; c < 5; ++c)
                    h5[c] = hw[c * HWC + ty * BW + tx];
            } else {
#pragma unroll
                for (int c = 0; c < 5; ++c) h5[c] = 0.0f;
            }
#pragma unroll
            for (int c = 0; c < 5; ++c) sa[c] += h5[c];
            const int dout = d0 + t - 8;
            if (t >= 8 && dout < Dd) {
                const float cross = sa[4] - sa[0] * sa[1] * INV_WV;
                const float iv    = sa[2] - sa[0] * sa[0] * INV_WV;
                const float jv    = sa[3] - sa[1] * sa[1] * INV_WV;
                acc += (cross * cross) * __builtin_amdgcn_rcpf(iv * jv + 1e-5f);
            }
#pragma unroll
            for (int c = 0; c < 5; ++c) sa[c] -= hist[(u + 1) % 9][c];
#pragma unroll
            for (int c = 0; c < 5; ++c) hist[u][c] = h5[c];
        }
    }
#undef ISSUE

    // ---- block reduction + global atomic (pre-scaled) ----
    red[tid] = acc;
    __syncthreads();
    for (int off = NT / 2; off > 0; off >>= 1) {
        if (tid < off) red[tid] += red[tid + off];
        __syncthreads();
    }
    if (tid == 0) atomicAdd(out, red[0] * NEG_INV_TOTAL);
}

extern "C" void kernel_launch(void* const* d_in, const int* in_sizes, int n_in,
                              void* d_out, int out_size, void* d_ws, size_t ws_size,
                              hipStream_t stream) {
    const float* I = (const float*)d_in[0];
    const float* J = (const float*)d_in[1];
    float* out = (float*)d_out;

    hipMemsetAsync(d_out, 0, sizeof(float), stream);   // stream-ordered, graph-safe
    k_ncc<<<NBLK, NT, 0, stream>>>(I, J, out);
}